// Round 1
// 366.857 us; speedup vs baseline: 1.0861x; 1.0861x over previous
//
#include <hip/hip_runtime.h>
#include <hip/hip_bf16.h>

// Sizes (fixed by the problem)
#define B_    64
#define N_    100
#define R_    9900
#define OBJD  5
#define EFF   100

typedef __bf16 bf16x8 __attribute__((ext_vector_type(8)));
typedef __bf16 bf16x2 __attribute__((ext_vector_type(2)));
typedef short  short8v __attribute__((ext_vector_type(8)));
typedef float  f32x4  __attribute__((ext_vector_type(4)));

// Native f32->bf16 (RNE). Compiler emits v_cvt_pk_bf16_f32 (1 op / pair);
// the old manual bit-twiddle was 4 VALU ops per conversion.
__device__ __forceinline__ ushort f2bf(float f) {
    __bf16 h = (__bf16)f;
    return __builtin_bit_cast(ushort, h);
}
__device__ __forceinline__ unsigned pk2(float a, float b) {
    bf16x2 v; v[0] = (__bf16)a; v[1] = (__bf16)b;
    return __builtin_bit_cast(unsigned, v);
}
__device__ __forceinline__ float bf2f(ushort u) {
    union { unsigned u; float f; } x; x.u = ((unsigned)u) << 16;
    return x.f;
}

// ---------------------------------------------------------------------------
// Prepped weight region WTR (ushort offsets) — unchanged (validated):
//   rel P1 @0      [160c][40k]   W1 (c<150, k<11)          6400
//   rel P2 @6400   [160c][168k]  W2 (c<150, k<150)        26880
//   rel P3 @33280  [112c][168k]  W3 (c<100, k<150)        18816
//   obj imgs @52096: 8 x [160c][72k] chunk images (oW1 remapped, oW2, oW3)
// ---------------------------------------------------------------------------
#define WTR_OBJ 52096

__global__ __launch_bounds__(256) void k_prepw(
    const float* __restrict__ W1, const float* __restrict__ W2,
    const float* __restrict__ W3, const float* __restrict__ O1,
    const float* __restrict__ O2, const float* __restrict__ O3,
    ushort* __restrict__ WTR)
{
    const int img = blockIdx.x;   // 0..10
    if (img == 0) {
        for (int idx = threadIdx.x; idx < 6400; idx += 256) {
            const int c = idx / 40, k = idx - (idx/40)*40;
            WTR[idx] = f2bf((c < 150 && k < 11) ? W1[k*150 + c] : 0.f);
        }
    } else if (img == 1) {
        for (int idx = threadIdx.x; idx < 26880; idx += 256) {
            const int c = idx / 168, k = idx - (idx/168)*168;
            WTR[6400 + idx] = f2bf((c < 150 && k < 150) ? W2[k*150 + c] : 0.f);
        }
    } else if (img == 2) {
        for (int idx = threadIdx.x; idx < 18816; idx += 256) {
            const int c = idx / 168, k = idx - (idx/168)*168;
            WTR[33280 + idx] = f2bf((c < 100 && k < 150) ? W3[k*100 + c] : 0.f);
        }
    } else {
        const int j = img - 3;   // 0..7
        ushort* dst = WTR + WTR_OBJ + (size_t)j*11520;
        for (int idx = threadIdx.x; idx < 11520; idx += 256) {
            const int cc = idx / 72, kk = idx - (idx/72)*72;
            float v = 0.f;
            if (kk < 64) {
                if (j < 4) {            // oW1, remapped input cols
                    const int kg = j*64 + kk;
                    int row = -1;
                    if (kg < 5) row = kg;
                    else if (kg >= 8 && kg < 108) row = kg - 3;      // ER hi
                    else if (kg >= 108 && kg < 208) row = kg - 103;  // ER lo
                    if (cc < 100 && row >= 0) v = O1[row*100 + cc];
                } else if (j < 6) {     // oW2
                    const int kg = (j-4)*64 + kk;
                    if (cc < 100 && kg < 100) v = O2[kg*100 + cc];
                } else {                // oW3
                    const int kg = (j-6)*64 + kk;
                    if (cc < 2 && kg < 100) v = O3[kg*2 + cc];
                }
            }
            dst[idx] = f2bf(v);
        }
    }
}

// ---------------------------------------------------------------------------
// K2: persistent fused gather + relational MLP + FUSED SCATTER.
// Grid 256 (=CU count), 512 threads (8 waves), 1 block/CU.
// Block (b, qt): batch b, r-quarter qt -> tiles of 64 r's.
// This round: gather output moved to dedicated gbuf[64][24] (kills L1's
// mid-phase barrier + per-tile zero-fill), all f32->bf16 via v_cvt_pk,
// per-qt ER slabs (plain stores, no cross-XCD atomics, no memset).
// LDS (ushort offsets):
// ---------------------------------------------------------------------------
#define LW1 0        // [160][40]   6400
#define LW2 6400     // [160][168]  26880
#define LW3 33280    // [112][168]  18816
#define LBA 52096    // [112][72]   8064  (SR stage / ebuf; rows 100..111 zero)
#define LBB 60160    // [112][72]   8064  (RR stage; rows 100..111 zero)
#define LACT 68224   // [64][168]   10752
#define LBIAS 78976  // 400 fp32    800
#define LGB  79776   // [64][24]    1536  (gather output; cols 11..23 zeroed once)
#define LTOT 81312   // 162,624 B  (<= 163,840)

__global__ __launch_bounds__(512, 1) void k_relmlp_p(
    const float* __restrict__ obj, const float* __restrict__ SR,
    const float* __restrict__ RR, const float* __restrict__ RI,
    const ushort* __restrict__ WTR,
    const float* __restrict__ b1, const float* __restrict__ b2,
    const float* __restrict__ b3, float* __restrict__ ER)
{
    __shared__ __align__(16) ushort lds[LTOT];
    const int t  = threadIdx.x;
    const int b  = blockIdx.x >> 2;
    const int qt = blockIdx.x & 3;
    const int lane = t & 63, w = t >> 6;
    const int lo = lane & 15, hi = lane >> 4;
    const int mt = w & 3, nh = w >> 2;      // m-tile, n-half (MLP phases)
    const int q  = t & 7,  rr = t >> 3;     // gather: 8 lanes per row

    // ---- block-start: weights, biases to LDS; zero pads ----
    #pragma unroll
    for (int j = 0; j < 13; ++j) {
        const int idx = t + j*512;
        if (idx < 6512)
            reinterpret_cast<uint4*>(lds)[idx] =
                reinterpret_cast<const uint4*>(WTR)[idx];
    }
    {
        float* bias_w = (float*)(lds + LBIAS);
        if (t < 150)      bias_w[t] = b1[t];
        else if (t < 300) bias_w[t] = b2[t-150];
        else if (t < 400) bias_w[t] = b3[t-300];
    }
    if (t < 216) {   // rows 100..111 of bufA/bufB = 108 uint4 each
        ushort* base = lds + ((t < 108) ? LBA : LBB) + 100*72;
        const int k = (t < 108) ? t : t - 108;
        *reinterpret_cast<uint4*>(base + k*8) = make_uint4(0u, 0u, 0u, 0u);
    }
    if (t < 64) {    // gbuf static pad cols 11..23 (cols 0..10 rewritten/tile)
        ushort* gb0 = lds + LGB + t*24;
        gb0[11] = 0;
        *reinterpret_cast<ushort4*>(&gb0[12]) = make_ushort4(0,0,0,0);
        *reinterpret_cast<ushort4*>(&gb0[16]) = make_ushort4(0,0,0,0);
        *reinterpret_cast<ushort4*>(&gb0[20]) = make_ushort4(0,0,0,0);
    }

    // ---- obj slice to registers: q-lane covers n = q*13 .. q*13+12 ----
    float objv[13][5];
    {
        const int n0 = q*13;
        #pragma unroll
        for (int i = 0; i < 13; ++i) {
            const int n = n0 + i;
            #pragma unroll
            for (int d = 0; d < 5; ++d)
                objv[i][d] = (n < N_) ? obj[(size_t)b*500 + n*5 + d] : 0.f;
        }
    }

    const int tile0 = qt*39;
    const int tile1 = (tile0 + 39 < 155) ? tile0 + 39 : 155;

    ushort* bufA = lds + LBA;
    ushort* bufB = lds + LBB;
    ushort* act  = lds + LACT;
    ushort* gb   = lds + LGB;
    const float* bias = (const float*)(lds + LBIAS);

    f32x4 acc_er[7];
    #pragma unroll
    for (int ct = 0; ct < 7; ++ct) acc_er[ct] = (f32x4){0.f, 0.f, 0.f, 0.f};

    float4 psr[4], prr[4];
    float pri = 0.f, pri_n = 0.f;
    auto load4 = [&](float4* p, const float* M, int tile) {
        const int rr0 = tile*64;
        const int nr = (R_ - rr0 < 64) ? R_ - rr0 : 64;
        #pragma unroll
        for (int i = 0; i < 4; ++i) {
            const int idx = t + i*512;
            const int ci = idx < 1600 ? idx : 1599;
            const int n = ci >> 4, qq = ci & 15;
            const int col = (qq*4 < nr) ? qq*4 : 0;
            p[i] = *reinterpret_cast<const float4*>(
                &M[((size_t)b*N_ + n)*R_ + rr0 + col]);
        }
    };
    auto store4 = [&](const float4* p, ushort* dst, int nrow) {
        #pragma unroll
        for (int i = 0; i < 4; ++i) {
            const int idx = t + i*512;
            if (idx < 1600) {
                const int n = idx >> 4, qq = idx & 15;
                float4 v = p[i];
                if (qq*4 >= nrow) v = make_float4(0.f, 0.f, 0.f, 0.f);
                uint2 u; u.x = pk2(v.x, v.y); u.y = pk2(v.z, v.w);
                *reinterpret_cast<uint2*>(&dst[n*72 + qq*4]) = u;
            }
        }
    };
    auto loadRI = [&](int tile) -> float {
        const int rr0 = tile*64;
        return (t < 64 && rr0 + t < R_) ? RI[(size_t)b*R_ + rr0 + t] : 0.f;
    };

    load4(psr, SR, tile0);
    load4(prr, RR, tile0);
    pri = loadRI(tile0);
    __syncthreads();                       // resident LDS + pads ready

    for (int tile = tile0; tile < tile1; ++tile) {
        const int r0 = tile*64;
        const int nrow = (R_ - r0 < 64) ? R_ - r0 : 64;

        // ---- stage SR->bufA, RR->bufB; prefetch next tile ----
        store4(psr, bufA, nrow);
        store4(prr, bufB, nrow);
        if (tile + 1 < tile1) {
            load4(psr, SR, tile+1);
            load4(prr, RR, tile+1);
            pri_n = loadRI(tile+1);
        }
        __syncthreads();

        // ---- gather: 8 lanes/row, obj in VGPR, single merged pass ----
        {
            float s0=0.f,s1=0.f,s2=0.f,s3=0.f,s4=0.f;
            float g0=0.f,g1=0.f,g2=0.f,g3=0.f,g4=0.f;
            const int n0 = q*13;
            #pragma unroll
            for (int i = 0; i < 13; ++i) {
                const int n = n0 + i;   // n>=100 rows are zeroed pad -> safe
                const float ms = bf2f(bufA[n*72 + rr]);
                const float mr = bf2f(bufB[n*72 + rr]);
                s0 += ms*objv[i][0]; s1 += ms*objv[i][1]; s2 += ms*objv[i][2];
                s3 += ms*objv[i][3]; s4 += ms*objv[i][4];
                g0 += mr*objv[i][0]; g1 += mr*objv[i][1]; g2 += mr*objv[i][2];
                g3 += mr*objv[i][3]; g4 += mr*objv[i][4];
            }
            #pragma unroll
            for (int msk = 1; msk < 8; msk <<= 1) {
                s0 += __shfl_xor(s0, msk); s1 += __shfl_xor(s1, msk);
                s2 += __shfl_xor(s2, msk); s3 += __shfl_xor(s3, msk);
                s4 += __shfl_xor(s4, msk);
                g0 += __shfl_xor(g0, msk); g1 += __shfl_xor(g1, msk);
                g2 += __shfl_xor(g2, msk); g3 += __shfl_xor(g3, msk);
                g4 += __shfl_xor(g4, msk);
            }
            if (q < 5) {
                const float sv = (q==0)?s0:(q==1)?s1:(q==2)?s2:(q==3)?s3:s4;
                const float gv = (q==0)?g0:(q==1)?g1:(q==2)?g2:(q==3)?g3:g4;
                gb[rr*24 + q]     = f2bf(sv);
                gb[rr*24 + 5 + q] = f2bf(gv);
            }
            if (t < 64) gb[t*24 + 10] = f2bf(pri);   // RI col
            pri = pri_n;
        }
        __syncthreads();

        // ---- L1: 11(32) -> 150   (reads gbuf, writes act: no mid-barrier) ----
        {
            f32x4 acc[5];
            #pragma unroll
            for (int j = 0; j < 5; ++j) {
                const int c = (nh*5 + j)*16 + lo;
                const float bv = (c < 150) ? bias[c] : 0.f;
                acc[j][0]=bv; acc[j][1]=bv; acc[j][2]=bv; acc[j][3]=bv;
            }
            bf16x8 a = __builtin_bit_cast(bf16x8, (short8v)0);
            if (hi < 2)     // k 16..31 zero (W1 image is zero there too)
                a = *reinterpret_cast<const bf16x8*>(
                    &gb[(mt*16 + lo)*24 + hi*8]);
            #pragma unroll
            for (int j = 0; j < 5; ++j) {
                const int ct = nh*5 + j;
                const bf16x8 bb = *reinterpret_cast<const bf16x8*>(
                    &lds[LW1 + (ct*16 + lo)*40 + hi*8]);
                acc[j] = __builtin_amdgcn_mfma_f32_16x16x32_bf16(a, bb, acc[j], 0,0,0);
            }
            #pragma unroll
            for (int j = 0; j < 5; ++j) {
                const int ct = nh*5 + j;
                #pragma unroll
                for (int r = 0; r < 4; ++r)
                    act[(mt*16 + hi*4 + r)*168 + ct*16 + lo] =
                        f2bf(fmaxf(acc[j][r], 0.f));
            }
            __syncthreads();
        }
        // ---- L2: 150(160) -> 150 ----
        {
            f32x4 acc[5];
            #pragma unroll
            for (int j = 0; j < 5; ++j) {
                const int c = (nh*5 + j)*16 + lo;
                const float bv = (c < 150) ? bias[150 + c] : 0.f;
                acc[j][0]=bv; acc[j][1]=bv; acc[j][2]=bv; acc[j][3]=bv;
            }
            #pragma unroll
            for (int ks = 0; ks < 5; ++ks) {
                const bf16x8 a = *reinterpret_cast<const bf16x8*>(
                    &act[(mt*16 + lo)*168 + ks*32 + hi*8]);
                #pragma unroll
                for (int j = 0; j < 5; ++j) {
                    const int ct = nh*5 + j;
                    const bf16x8 bb = *reinterpret_cast<const bf16x8*>(
                        &lds[LW2 + (ct*16 + lo)*168 + ks*32 + hi*8]);
                    acc[j] = __builtin_amdgcn_mfma_f32_16x16x32_bf16(a, bb, acc[j], 0,0,0);
                }
            }
            __syncthreads();
            #pragma unroll
            for (int j = 0; j < 5; ++j) {
                const int ct = nh*5 + j;
                #pragma unroll
                for (int r = 0; r < 4; ++r)
                    act[(mt*16 + hi*4 + r)*168 + ct*16 + lo] =
                        f2bf(fmaxf(acc[j][r], 0.f));
            }
            __syncthreads();
        }
        // ---- L3: 150(160) -> 100, transposed to ebuf (bufA) ----
        {
            const int nct = nh ? 3 : 4;
            f32x4 acc[4];
            #pragma unroll
            for (int j = 0; j < 4; ++j) {
                const int c = (nh*4 + j)*16 + lo;
                const float bv = (c < 100) ? bias[300 + c] : 0.f;
                acc[j][0]=bv; acc[j][1]=bv; acc[j][2]=bv; acc[j][3]=bv;
            }
            #pragma unroll
            for (int ks = 0; ks < 5; ++ks) {
                const bf16x8 a = *reinterpret_cast<const bf16x8*>(
                    &act[(mt*16 + lo)*168 + ks*32 + hi*8]);
                #pragma unroll
                for (int j = 0; j < 4; ++j) {
                    if (j < nct) {
                        const int ct = nh*4 + j;
                        const bf16x8 bb = *reinterpret_cast<const bf16x8*>(
                            &lds[LW3 + (ct*16 + lo)*168 + ks*32 + hi*8]);
                        acc[j] = __builtin_amdgcn_mfma_f32_16x16x32_bf16(a, bb, acc[j], 0,0,0);
                    }
                }
            }
            // bufA (SR) already consumed by gather -> write ebuf, no pre-barrier
            #pragma unroll
            for (int j = 0; j < 4; ++j) {
                if (j < nct) {
                    const int e = (nh*4 + j)*16 + lo;
                    if (e < 100) {
                        uint2 u;
                        u.x = pk2(fmaxf(acc[j][0], 0.f), fmaxf(acc[j][1], 0.f));
                        u.y = pk2(fmaxf(acc[j][2], 0.f), fmaxf(acc[j][3], 0.f));
                        *reinterpret_cast<uint2*>(&bufA[e*72 + mt*16 + hi*4]) = u;
                    }
                }
            }
            __syncthreads();   // ebuf complete before scatter reads
        }

        // ---- fused scatter: acc_er += RR_tile x E_tile ----
        // A[row=n][k=r] from bufB; B[k=r][col=e] from ebuf (bufA).
        // r >= nrow contributes zero via bufB's zeroed cols. Waves 0..6 = 7
        // n-tiles (rows 0..111; 100..111 are zero pad rows).
        if (w < 7) {
            #pragma unroll
            for (int ks = 0; ks < 2; ++ks) {
                const bf16x8 a = *reinterpret_cast<const bf16x8*>(
                    &bufB[(w*16 + lo)*72 + ks*32 + hi*8]);
                #pragma unroll
                for (int ct = 0; ct < 7; ++ct) {
                    const bf16x8 bb = *reinterpret_cast<const bf16x8*>(
                        &bufA[(ct*16 + lo)*72 + ks*32 + hi*8]);
                    acc_er[ct] = __builtin_amdgcn_mfma_f32_16x16x32_bf16(
                        a, bb, acc_er[ct], 0, 0, 0);
                }
            }
        }
        __syncthreads();   // scatter reads done before next tile's staging
    }

    // ---- ER partials: plain stores to this block's qt-slab (no atomics) ----
    if (w < 7) {
        float* ERq = ER + ((size_t)qt*B_ + b)*(size_t)(N_*EFF);
        #pragma unroll
        for (int ct = 0; ct < 7; ++ct) {
            const int e = ct*16 + lo;
            if (e < EFF) {
                #pragma unroll
                for (int rg = 0; rg < 4; ++rg) {
                    const int n = w*16 + hi*4 + rg;
                    if (n < N_)
                        ERq[n*EFF + e] = acc_er[ct][rg];
                }
            }
        }
    }
}

// ---------------------------------------------------------------------------
// Weight-image register staging (validated).
// ---------------------------------------------------------------------------
__device__ __forceinline__ void img_load(const ushort* __restrict__ g,
                                         uint4* pre, int t) {
    #pragma unroll
    for (int j = 0; j < 6; ++j) {
        int idx = t + j*256;
        int cidx = idx < 1440 ? idx : 1439;
        pre[j] = *reinterpret_cast<const uint4*>(g + (size_t)cidx*8);
    }
}
__device__ __forceinline__ void img_store(const uint4* pre, ushort* wt, int t) {
    #pragma unroll
    for (int j = 0; j < 6; ++j) {
        int idx = t + j*256;
        if (idx < 1440)
            *reinterpret_cast<uint4*>(wt + (size_t)idx*8) = pre[j];
    }
}

// ---------------------------------------------------------------------------
// MFMA dense layer for objmlp (validated round 6).
// ---------------------------------------------------------------------------
template<int COUT, int NCHUNK, int LASTKS, int NCT, bool RELU, int EPI, int ASTR>
__device__ __forceinline__ void mfma_layerO(
    const ushort* __restrict__ WT, const float* __restrict__ Bias,
    ushort* act, ushort* wt, int t, float* gout, int grow0)
{
    const int lane = t & 63;
    const int wv   = t >> 6;
    const int lo   = lane & 15;
    const int hi   = lane >> 4;

    f32x4 acc[2][NCT];
    #pragma unroll
    for (int ct = 0; ct < NCT; ++ct) {
        const int c = ct*16 + lo;
        const float bv = (c < COUT) ? Bias[c] : 0.f;
        #pragma unroll
        for (int m = 0; m < 2; ++m) {
            acc[m][ct][0] = bv; acc[m][ct][1] = bv;
            acc[m][ct][2] = bv; acc[m][ct][3] = bv;
        }
    }

    uint4 pre[6];
    img_load(WT, pre, t);
    #pragma unroll
    for (int q = 0; q < NCHUNK; ++q) {
        __syncthreads();
        img_store(pre, wt, t);
        if (q + 1 < NCHUNK) img_load(WT + (size_t)(q+1)*11520, pre, t);
        __syncthreads();
        const int nks = (q == NCHUNK-1) ? LASTKS : 2;
        #pragma unroll
        for (int ks = 0; ks < 2; ++ks) {
            if (ks < nks) {
                const int kg = q*64 + ks*32;
                const bf16x8 a0 = *reinterpret_cast<const bf16x8*>(
                    &act[(wv*32 +      lo)*ASTR + kg + hi*8]);
                const bf16x8 a1 = *reinterpret_cast<const bf16x8*>(
                    &act[(wv*32 + 16 + lo)*ASTR + kg + hi*8]);
                #pragma unroll
                for (int ct = 0; ct < NCT; ++ct) {
                    const bf16x8 b = *reinterpret_cast<const bf16x8*>(
                        &wt[(ct*16 + lo)*72 + ks*32 + hi*8]);
                    acc[0][ct] = __builtin_amdgcn_mfma_f32_16x16x32_bf16(
                        a0, b, acc[0][ct], 0, 0, 0);
                    acc[1][ct] = __builtin_amdgcn_mfma_f32_16x16x32_bf16(
                        a1, b, acc[1][ct], 0, 0, 0);
                }
            }
        }
    }

    __syncthreads();
    if (EPI == 0) {
        #pragma unroll
        for (int m = 0; m < 2; ++m)
            #pragma unroll
            for (int ct = 0; ct < NCT; ++ct)
                #pragma unroll
                for (int r = 0; r < 4; ++r) {
                    float v = acc[m][ct][r];
                    if (RELU) v = fmaxf(v, 0.f);
                    act[(wv*32 + m*16 + hi*4 + r)*ASTR + ct*16 + lo] = f2bf(v);
                }
    } else {
        #pragma unroll
        for (int m = 0; m < 2; ++m)
            #pragma unroll
            for (int r = 0; r < 4; ++r)
                if (lo < 2)
                    gout[(size_t)(grow0 + wv*32 + m*16 + hi*4 + r)*2 + lo] =
                        acc[m][0][r];
    }
    __syncthreads();
}

// ---------------------------------------------------------------------------
// K4: object MLP via MFMA (validated round 6). 50 blocks x 128 rows.
// ER is now 4 per-qt slabs; sum them during the load.
// ---------------------------------------------------------------------------
#define OSTR 232
#define ERSL ((size_t)B_*N_*EFF)

__global__ __launch_bounds__(256, 1) void k_objmlp_mfma(
    const float* __restrict__ obj, const float* __restrict__ ER,
    const ushort* __restrict__ WO,
    const float* __restrict__ ob1, const float* __restrict__ ob2,
    const float* __restrict__ ob3, float* __restrict__ out)
{
    __shared__ __align__(16) ushort act[128*OSTR];
    __shared__ __align__(16) ushort wt[160*72];
    const int t = threadIdx.x;
    const int rowbase = blockIdx.x * 128;

    float4 per[13];
    #pragma unroll
    for (int j = 0; j < 13; ++j) {
        const int idx = t + j*256;
        const int ci = idx < 3200 ? idx : 3199;
        const int row = ci / 25, c = ci - row*25;
        const float* p = &ER[(size_t)(rowbase + row)*100 + c*4];
        const float4 a0 = *reinterpret_cast<const float4*>(p);
        const float4 a1 = *reinterpret_cast<const float4*>(p + ERSL);
        const float4 a2 = *reinterpret_cast<const float4*>(p + 2*ERSL);
        const float4 a3 = *reinterpret_cast<const float4*>(p + 3*ERSL);
        per[j] = make_float4(a0.x + a1.x + a2.x + a3.x,
                             a0.y + a1.y + a2.y + a3.y,
                             a0.z + a1.z + a2.z + a3.z,
                             a0.w + a1.w + a2.w + a3.w);
    }
    #pragma unroll
    for (int j = 0; j < 13; ++j) {
        const int idx = t + j*256;
        if (idx < 3200) {
            const int row = idx / 25, c = idx - row*25;
            ushort h[4], l[4];
            #pragma unroll
            for (int k = 0; k < 4; ++k) {
                const float f = ((const float*)&per[j])[k];
                h[k] = f2bf(f);
                l[k] = f2bf(f - bf2f(h[k]));
            }
            *reinterpret_cast<ushort4*>(&act[row*OSTR + 8 + c*4]) =
                make_ushort4(h[0], h[1], h[2], h[3]);
            *reinterpret_cast<ushort4*>(&act[row*OSTR + 108 + c*4]) =
                make_ushort4(l[0], l[1], l[2], l[3]);
        }
    }
    #pragma unroll
    for (int j = 0; j < 3; ++j) {
        const int idx = t + j*256;
        if (idx < 640) {
            const int row = idx / 5, d = idx - row*5;
            act[row*OSTR + d] = f2bf(obj[(size_t)(rowbase + row)*5 + d]);
        }
    }
    #pragma unroll
    for (int j = 0; j < 2; ++j) {
        const int idx = t + j*256;
        if (idx < 384) {
            const int row = idx / 3, c = 5 + (idx - row*3);
            act[row*OSTR + c] = 0;
        }
    }
    #pragma unroll
    for (int j = 0; j < 2; ++j) {
        const int idx = t + j*256;
        if (idx < 512) {
            const int row = idx >> 2, p = idx & 3;
            *reinterpret_cast<ushort4*>(&act[row*OSTR + 208 + p*4]) =
                make_ushort4(0, 0, 0, 0);
        }
    }

    mfma_layerO<100, 4, 1, 7, true,  0, OSTR>(WO,           ob1, act, wt, t, nullptr, 0);
    mfma_layerO<100, 2, 2, 7, true,  0, OSTR>(WO + 4*11520, ob2, act, wt, t, nullptr, 0);
    mfma_layerO<2,   2, 2, 1, false, 2, OSTR>(WO + 6*11520, ob3, act, wt, t, out, rowbase);
}

// ---------------------------------------------------------------------------
extern "C" void kernel_launch(void* const* d_in, const int* in_sizes, int n_in,
                              void* d_out, int out_size, void* d_ws, size_t ws_size,
                              hipStream_t stream)
{
    const float* objects = (const float*)d_in[0];
    const float* SR      = (const float*)d_in[1];
    const float* RR      = (const float*)d_in[2];
    const float* RI      = (const float*)d_in[3];
    const float* rW1 = (const float*)d_in[4];  const float* rb1 = (const float*)d_in[5];
    const float* rW2 = (const float*)d_in[6];  const float* rb2 = (const float*)d_in[7];
    const float* rW3 = (const float*)d_in[8];  const float* rb3 = (const float*)d_in[9];
    const float* oW1 = (const float*)d_in[10]; const float* ob1 = (const float*)d_in[11];
    const float* oW2 = (const float*)d_in[12]; const float* ob2 = (const float*)d_in[13];
    const float* oW3 = (const float*)d_in[14]; const float* ob3 = (const float*)d_in[15];
    float* out = (float*)d_out;

    // Workspace layout (~10.5 MB; ws held >129 MB in earlier E_T versions):
    //   ERp  fp32 [4 qt][B*N][100] = 10,240,000 B  @0   (fully written, no memset)
    //   WTR  bf16 144,256 ushorts  =    288,512 B  @10,240,000
    char* ws = (char*)d_ws;
    float*  ERp = (float*)ws;
    ushort* WTR = (ushort*)(ws + (size_t)4*B_*N_*EFF*sizeof(float));

    k_prepw<<<dim3(11), 256, 0, stream>>>(rW1, rW2, rW3, oW1, oW2, oW3, WTR);

    k_relmlp_p<<<dim3(256), 512, 0, stream>>>(objects, SR, RR, RI, WTR,
                                              rb1, rb2, rb3, ERp);

    k_objmlp_mfma<<<dim3(50), 256, 0, stream>>>(objects, ERp, WTR + WTR_OBJ,
                                                ob1, ob2, ob3, out);
}